// Round 7
// baseline (190.999 us; speedup 1.0000x reference)
//
#include <hip/hip_runtime.h>
#include <math.h>

#define EPS 1e-8f
constexpr int D     = 1024;
constexpr int NEMB  = 80;
constexpr int K     = 1849;
constexpr int BATCH = 4;
constexpr int P     = 43;
constexpr int TGT   = 602;
constexpr int ROWS  = BATCH * K;                   // 7396
constexpr size_t PLANE = (size_t)BATCH * NEMB * K; // 591,680
constexpr int SPLIT = 8;
constexpr int KC    = D / SPLIT;                   // 128

typedef float nfloat4 __attribute__((ext_vector_type(4))); // native vec for nontemporal builtins

// ---------------- bicubic tap weights (exact fp64, matches numpy) -----------
__device__ inline double cubic_w(double x) {
  const double A = -0.75;
  x = fabs(x);
  if (x <= 1.0) return ((A + 2.0) * x - (A + 3.0)) * x * x + 1.0;
  if (x < 2.0)  return A * (((x - 5.0) * x + 8.0) * x - 4.0);
  return 0.0;
}

__device__ inline float block_reduce_sum256(float v) {
  #pragma unroll
  for (int off = 32; off > 0; off >>= 1) v += __shfl_down(v, off, 64);
  __shared__ float red[4];
  int lane = threadIdx.x & 63, wid = threadIdx.x >> 6;
  if (lane == 0) red[wid] = v;
  __syncthreads();
  float r = 0.f;
  if (threadIdx.x == 0) r = red[0] + red[1] + red[2] + red[3];
  return r;
}

// blocks 0..79: e_norm rows; block 80: the 14-entry periodic weight table.
__global__ __launch_bounds__(256) void prep_kernel(
    const float* __restrict__ emb, float* __restrict__ e_norm,
    float4* __restrict__ gtw) {
  int bid = blockIdx.x;
  if (bid < NEMB) {
    float4 v = ((const float4*)(emb + (size_t)bid * D))[threadIdx.x];
    float s = v.x * v.x + v.y * v.y + v.z * v.z + v.w * v.w;
    s = block_reduce_sum256(s);
    if (threadIdx.x == 0) e_norm[bid] = sqrtf(s);
  } else {
    int j = threadIdx.x;
    if (j < 14) {
      double scale = (double)P / (double)TGT;
      double src = ((double)j + 0.5) * scale - 0.5;
      double fb = floor(src);
      double t = src - fb;
      float4 w;
      w.x = (float)cubic_w(t + 1.0);
      w.y = (float)cubic_w(t);
      w.z = (float)cubic_w(t - 1.0);
      w.w = (float)cubic_w(t - 2.0);
      gtw[j] = w;
    }
  }
}

// -------- split-K GEMM, 2-phase pipelined (prefetch tile t+1 during compute)
constexpr int BM  = 64;
constexpr int BK  = 32;
constexpr int LDA = 36; // padded LDS row stride (floats), 16B aligned
constexpr int NT  = KC / BK; // 4 K-tiles per block

__device__ inline float dot4(float4 v) {
  return v.x * v.x + v.y * v.y + v.z * v.z + v.w * v.w;
}

__global__ __launch_bounds__(256) void gemm_partial(
    const float* __restrict__ feats, const float* __restrict__ emb,
    float* __restrict__ part, float* __restrict__ fpart) {
  __shared__ float As[BM * LDA];
  __shared__ float Bs[NEMB * LDA];
  int t = threadIdx.x;
  int row0 = blockIdx.x * BM;
  int s = blockIdx.y;
  int tr = t >> 4, tc = t & 15;
  float acc[4][5] = {{0.f}};
  float ssq0 = 0.f, ssq1 = 0.f;

  int r = t >> 3, dg = t & 7;         // staging: 8 threads/row, 4 floats each
  int gr0 = row0 + r, gr1 = row0 + 32 + r;
  bool ok0 = gr0 < ROWS, ok1 = gr1 < ROWS;
  const float* pA0 = feats + (size_t)gr0 * D + dg * 4;
  const float* pA1 = feats + (size_t)gr1 * D + dg * 4;
  const float* pB0 = emb + (size_t)r * D + dg * 4;          // rows 0..31
  const float* pB1 = emb + (size_t)(32 + r) * D + dg * 4;   // rows 32..63
  const float* pB2 = emb + (size_t)(64 + r) * D + dg * 4;   // rows 64..79 (t<128)
  bool okB2 = t < 128;

  int kbeg = s * KC;
  const float4 zero = make_float4(0.f, 0.f, 0.f, 0.f);
  float4 a0 = ok0 ? *(const float4*)(pA0 + kbeg) : zero;
  float4 a1 = ok1 ? *(const float4*)(pA1 + kbeg) : zero;
  float4 b0 = *(const float4*)(pB0 + kbeg);
  float4 b1 = *(const float4*)(pB1 + kbeg);
  float4 b2 = okB2 ? *(const float4*)(pB2 + kbeg) : zero;

  for (int tile = 0; tile < NT; ++tile) {
    // phase A: commit prefetched regs to LDS (+ssq)
    ssq0 += dot4(a0);
    *(float4*)(As + r * LDA + dg * 4) = a0;
    ssq1 += dot4(a1);
    *(float4*)(As + (32 + r) * LDA + dg * 4) = a1;
    *(float4*)(Bs + r * LDA + dg * 4) = b0;
    *(float4*)(Bs + (32 + r) * LDA + dg * 4) = b1;
    if (okB2) *(float4*)(Bs + (64 + r) * LDA + dg * 4) = b2;
    __syncthreads();

    // phase B: issue next tile's loads (latency hides under the dd loop)
    if (tile + 1 < NT) {
      int k1 = kbeg + (tile + 1) * BK;
      a0 = ok0 ? *(const float4*)(pA0 + k1) : zero;
      a1 = ok1 ? *(const float4*)(pA1 + k1) : zero;
      b0 = *(const float4*)(pB0 + k1);
      b1 = *(const float4*)(pB1 + k1);
      if (okB2) b2 = *(const float4*)(pB2 + k1);
    }

    #pragma unroll
    for (int dd = 0; dd < BK; dd += 4) {
      float4 a[4], b[5];
      #pragma unroll
      for (int j = 0; j < 4; ++j)  a[j]  = *(const float4*)(As + (tr * 4 + j) * LDA + dd);
      #pragma unroll
      for (int i2 = 0; i2 < 5; ++i2) b[i2] = *(const float4*)(Bs + (tc + i2 * 16) * LDA + dd);
      #pragma unroll
      for (int j = 0; j < 4; ++j)
        #pragma unroll
        for (int i2 = 0; i2 < 5; ++i2)
          acc[j][i2] += a[j].x * b[i2].x + a[j].y * b[i2].y +
                        a[j].z * b[i2].z + a[j].w * b[i2].w;
    }
    __syncthreads();
  }

  #pragma unroll
  for (int off = 4; off > 0; off >>= 1) {
    ssq0 += __shfl_down(ssq0, off, 8);
    ssq1 += __shfl_down(ssq1, off, 8);
  }
  if ((t & 7) == 0) {
    if (gr0 < ROWS) fpart[(size_t)s * ROWS + gr0] = ssq0;
    if (gr1 < ROWS) fpart[(size_t)s * ROWS + gr1] = ssq1;
  }

  float* pplane = part + (size_t)s * PLANE;
  #pragma unroll
  for (int j = 0; j < 4; ++j) {
    int gr = row0 + tr * 4 + j;
    if (gr >= ROWS) continue;
    int b_ = gr / K;
    int k  = gr - b_ * K;
    #pragma unroll
    for (int i2 = 0; i2 < 5; ++i2) {
      int n = tc + i2 * 16;
      pplane[((size_t)(b_ * NEMB + n)) * K + k] = acc[j][i2];
    }
  }
}

// -------- reduce partials -> cosim (all loads/stores coalesced) --------------
__global__ __launch_bounds__(256) void reduce_kernel(
    const float* __restrict__ part, const float* __restrict__ fpart,
    const float* __restrict__ e_norm, float* __restrict__ cosim) {
  size_t e = (size_t)blockIdx.x * 256 + threadIdx.x;
  if (e >= PLANE) return;
  int bn = (int)(e / K);
  int k  = (int)(e - (size_t)bn * K);
  int b_ = bn / NEMB;
  int n  = bn - b_ * NEMB;
  int gr = b_ * K + k;
  float dot = 0.f, fn2 = 0.f;
  #pragma unroll
  for (int s = 0; s < SPLIT; ++s) {
    dot += part[(size_t)s * PLANE + e];
    fn2 += fpart[(size_t)s * ROWS + gr];
  }
  cosim[e] = dot / (sqrtf(fn2) * e_norm[n] + EPS);
}

// ---------------- separable bicubic resize (persistent, store-pipelined) -----
// grid = 1024 blocks x 320 threads (4 blocks/CU), each grid-strides over the
// 13,760 (bn,c) chunks. Per chunk: next chunk's 215 img floats prefetched into
// regs (latency hidden under compute+stores); nontemporal b128 store burst is
// issue-only (never awaited) so each CU emits a near-continuous write stream.
constexpr int NCHUNK = 320 * 43;   // 13,760
constexpr int RGRID  = 1024;

__global__ __launch_bounds__(320) void resize_kernel(
    const float* __restrict__ cosim, const float4* __restrict__ gtw,
    float* __restrict__ out) {
  __shared__ float img[5 * P];        // 860 B (always 5 clamped rows)
  __shared__ float4 wq[14];
  __shared__ float obuf[14 * TGT];    // 33,712 B packed output chunk

  int t = threadIdx.x;
  if (t < 14) wq[t] = gtw[t];

  // register prefetch of chunk's img tile: thread t<215 holds one float
  int hrel = t / P, col = t - hrel * P;   // valid for t<215
  auto img_load = [&](int cid) -> float {
    if (t >= 5 * P) return 0.f;
    int bn = cid / 43, c = cid - (cid / 43) * 43;
    int hmin = max(0, c - 2);
    int row = min(P - 1, hmin + hrel);
    return cosim[(size_t)bn * (P * P) + row * P + col];
  };

  int cid = blockIdx.x;
  float v = (cid < NCHUNK) ? img_load(cid) : 0.f;

  while (cid < NCHUNK) {
    int next = cid + RGRID;
    __syncthreads();                  // img free & all prior obuf reads done
    if (t < 5 * P) img[t] = v;
    if (next < NCHUNK) v = img_load(next);   // fire next loads early
    __syncthreads();                  // img ready

    int bn = cid / 43, c = cid - (cid / 43) * 43;

    if (t < TGT / 2) {
      int W0 = t * 2;
      int m0 = W0 / 14;
      int j0 = W0 - m0 * 14;
      int wb0 = m0 - 2 + (j0 >= 7);
      int j1 = (j0 == 13) ? 0 : j0 + 1;
      int d  = (j0 == 6) ? 1 : 0;
      float4 w0 = wq[j0], w1 = wq[j1];

      int i0 = min(P - 1, max(0, wb0));
      int i1 = min(P - 1, max(0, wb0 + 1));
      int i2 = min(P - 1, max(0, wb0 + 2));
      int i3 = min(P - 1, max(0, wb0 + 3));
      int i4 = min(P - 1, max(0, wb0 + 4));

      float ta[5], tb[5];
      #pragma unroll
      for (int h = 0; h < 5; ++h) {
        const float* rowp = img + h * P;
        float v0 = rowp[i0], v1 = rowp[i1], v2 = rowp[i2], v3 = rowp[i3], v4 = rowp[i4];
        ta[h] = w0.x * v0 + w0.y * v1 + w0.z * v2 + w0.w * v3;
        float u0 = d ? v1 : v0;
        float u1 = d ? v2 : v1;
        float u2 = d ? v3 : v2;
        float u3 = d ? v4 : v3;
        tb[h] = w1.x * u0 + w1.y * u1 + w1.z * u2 + w1.w * u3;
      }

      #define ROWS7(R0, a0, a1, a2, a3)                                        \
        _Pragma("unroll")                                                      \
        for (int r = R0; r < R0 + 7; ++r) {                                    \
          float4 hw = wq[r];                                                   \
          float ox = hw.x * ta[a0] + hw.y * ta[a1] + hw.z * ta[a2] + hw.w * ta[a3]; \
          float oy = hw.x * tb[a0] + hw.y * tb[a1] + hw.z * tb[a2] + hw.w * tb[a3]; \
          *(float2*)(obuf + r * TGT + W0) = make_float2(ox, oy);               \
        }

      if (c >= 2 && c <= 40) {
        ROWS7(0, 0, 1, 2, 3)
        ROWS7(7, 1, 2, 3, 4)
      } else if (c == 0) {
        ROWS7(0, 0, 0, 0, 1)
        ROWS7(7, 0, 0, 1, 2)
      } else if (c == 1) {
        ROWS7(0, 0, 0, 1, 2)
        ROWS7(7, 0, 1, 2, 3)
      } else if (c == 41) {
        ROWS7(0, 0, 1, 2, 3)
        ROWS7(7, 1, 2, 3, 3)
      } else {
        ROWS7(0, 0, 1, 2, 2)
        ROWS7(7, 1, 2, 2, 2)
      }
      #undef ROWS7
    }
    __syncthreads();                  // obuf ready

    // issue-only store burst: 2107 aligned 16B nontemporal stores
    nfloat4* dst = (nfloat4*)(out + (size_t)bn * TGT * TGT + (size_t)c * 14 * TGT);
    const nfloat4* sb = (const nfloat4*)obuf;
    constexpr int NVEC = 14 * TGT / 4; // 2107
    for (int i = t; i < NVEC; i += 320) {
      __builtin_nontemporal_store(sb[i], dst + i);
    }
    cid = next;
  }
}

// ---------------- launch ------------------------------------------------------
extern "C" void kernel_launch(void* const* d_in, const int* in_sizes, int n_in,
                              void* d_out, int out_size, void* d_ws, size_t ws_size,
                              hipStream_t stream) {
  const float* feats = (const float*)d_in[0];
  const float* emb   = (const float*)d_in[1];
  float* out = (float*)d_out;
  char* ws = (char*)d_ws;

  auto align64 = [](size_t x) { return (x + 63) & ~(size_t)63; };
  size_t off = 0;
  float* cosim  = (float*)(ws + off); off = align64(off + PLANE * 4);
  float* e_norm = (float*)(ws + off); off = align64(off + NEMB * 4);
  float4* gtw   = (float4*)(ws + off); off = align64(off + 14 * 16);

  float* fpart = (float*)(ws + off); off = align64(off + (size_t)SPLIT * ROWS * 4);
  float* part  = (float*)(ws + off); off = align64(off + (size_t)SPLIT * PLANE * 4);

  prep_kernel<<<dim3(NEMB + 1), dim3(256), 0, stream>>>(emb, e_norm, gtw);
  gemm_partial<<<dim3((ROWS + BM - 1) / BM, SPLIT), dim3(256), 0, stream>>>(
      feats, emb, part, fpart);
  reduce_kernel<<<dim3((int)((PLANE + 255) / 256)), dim3(256), 0, stream>>>(
      part, fpart, e_norm, cosim);
  resize_kernel<<<dim3(RGRID), dim3(320), 0, stream>>>(cosim, gtw, out);
}